// Round 1
// baseline (4471.562 us; speedup 1.0000x reference)
//
#include <hip/hip_runtime.h>

#define TPB 256

__global__ void k_init_deg(float* __restrict__ deg, int N) {
    int i = blockIdx.x * blockDim.x + threadIdx.x;
    if (i < N) deg[i] = 1.0f;   // self-loop
}

__global__ void k_count(const int* __restrict__ col, float* __restrict__ deg, int E) {
    int e = blockIdx.x * blockDim.x + threadIdx.x;
    if (e < E) atomicAdd(&deg[col[e]], 1.0f);
}

// dinv = rsqrt(deg) (in-place); h0 = x @ W1; g0 = dinv*h0; acc1 = g0 (self-loop init)
__global__ void k_node1(const float* __restrict__ x, const float* __restrict__ W1,
                        float* __restrict__ deg_dinv, float* __restrict__ g0,
                        float* __restrict__ acc1, int N) {
    int i = blockIdx.x * blockDim.x + threadIdx.x;
    if (i >= N) return;
    float dinv = rsqrtf(deg_dinv[i]);
    deg_dinv[i] = dinv;

    const float4* xv = (const float4*)(x + (size_t)i * 16);
    float4 a0 = xv[0], a1 = xv[1], a2 = xv[2], a3 = xv[3];
    float xl[16] = {a0.x, a0.y, a0.z, a0.w, a1.x, a1.y, a1.z, a1.w,
                    a2.x, a2.y, a2.z, a2.w, a3.x, a3.y, a3.z, a3.w};
    float h[8];
#pragma unroll
    for (int j = 0; j < 8; ++j) h[j] = 0.0f;
#pragma unroll
    for (int k = 0; k < 16; ++k) {
        float xk = xl[k];
#pragma unroll
        for (int j = 0; j < 8; ++j) h[j] += xk * W1[k * 8 + j];
    }
    float4 g_lo = make_float4(dinv * h[0], dinv * h[1], dinv * h[2], dinv * h[3]);
    float4 g_hi = make_float4(dinv * h[4], dinv * h[5], dinv * h[6], dinv * h[7]);
    float4* gv = (float4*)(g0 + (size_t)i * 8);
    float4* av = (float4*)(acc1 + (size_t)i * 8);
    gv[0] = g_lo; gv[1] = g_hi;
    av[0] = g_lo; av[1] = g_hi;
}

// acc1[col] += g0[row]  (8 channels)
__global__ void k_scatter1(const int* __restrict__ row, const int* __restrict__ col,
                           const float* __restrict__ g0, float* __restrict__ acc1, int E) {
    int e = blockIdx.x * blockDim.x + threadIdx.x;
    if (e >= E) return;
    int r = row[e], c = col[e];
    const float4* gv = (const float4*)(g0 + (size_t)r * 8);
    float4 lo = gv[0], hi = gv[1];
    float* dst = acc1 + (size_t)c * 8;
    atomicAdd(dst + 0, lo.x);
    atomicAdd(dst + 1, lo.y);
    atomicAdd(dst + 2, lo.z);
    atomicAdd(dst + 3, lo.w);
    atomicAdd(dst + 4, hi.x);
    atomicAdd(dst + 5, hi.y);
    atomicAdd(dst + 6, hi.z);
    atomicAdd(dst + 7, hi.w);
}

// h = relu(dinv*acc1 + b1); g1 = dinv*(h @ W2); acc2 = g1 (self-loop init)
__global__ void k_node2(const float* __restrict__ dinv_arr, const float* __restrict__ acc1,
                        const float* __restrict__ b1, const float* __restrict__ W2,
                        float* __restrict__ g1, float* __restrict__ acc2, int N) {
    int i = blockIdx.x * blockDim.x + threadIdx.x;
    if (i >= N) return;
    float dinv = dinv_arr[i];
    const float4* av = (const float4*)(acc1 + (size_t)i * 8);
    float4 lo = av[0], hi = av[1];
    float h[8] = {lo.x, lo.y, lo.z, lo.w, hi.x, hi.y, hi.z, hi.w};
    float o0 = 0.0f, o1 = 0.0f;
#pragma unroll
    for (int j = 0; j < 8; ++j) {
        float hj = fmaxf(dinv * h[j] + b1[j], 0.0f);
        o0 += hj * W2[j * 2 + 0];
        o1 += hj * W2[j * 2 + 1];
    }
    float2 g = make_float2(dinv * o0, dinv * o1);
    ((float2*)g1)[i] = g;
    ((float2*)acc2)[i] = g;
}

// acc2[col] += g1[row]  (2 channels)
__global__ void k_scatter2(const int* __restrict__ row, const int* __restrict__ col,
                           const float* __restrict__ g1, float* __restrict__ acc2, int E) {
    int e = blockIdx.x * blockDim.x + threadIdx.x;
    if (e >= E) return;
    int r = row[e], c = col[e];
    float2 g = ((const float2*)g1)[r];
    float* dst = acc2 + (size_t)c * 2;
    atomicAdd(dst + 0, g.x);
    atomicAdd(dst + 1, g.y);
}

// o = dinv*acc2 + b2; out = log_softmax(o)
__global__ void k_final(const float* __restrict__ dinv_arr, const float* __restrict__ acc2,
                        const float* __restrict__ b2, float* __restrict__ out, int N) {
    int i = blockIdx.x * blockDim.x + threadIdx.x;
    if (i >= N) return;
    float dinv = dinv_arr[i];
    float2 a = ((const float2*)acc2)[i];
    float o0 = dinv * a.x + b2[0];
    float o1 = dinv * a.y + b2[1];
    float m = fmaxf(o0, o1);
    float lse = m + logf(expf(o0 - m) + expf(o1 - m));
    ((float2*)out)[i] = make_float2(o0 - lse, o1 - lse);
}

extern "C" void kernel_launch(void* const* d_in, const int* in_sizes, int n_in,
                              void* d_out, int out_size, void* d_ws, size_t ws_size,
                              hipStream_t stream) {
    const float* x  = (const float*)d_in[0];
    const float* W1 = (const float*)d_in[1];
    const float* b1 = (const float*)d_in[2];
    const float* W2 = (const float*)d_in[3];
    const float* b2 = (const float*)d_in[4];
    const int*   ei = (const int*)d_in[5];

    const int N = in_sizes[0] / 16;
    const int E = in_sizes[5] / 2;
    const int* row = ei;
    const int* col = ei + E;

    float* ws   = (float*)d_ws;
    float* deg  = ws;              // N floats: deg, then dinv (in-place)
    float* g0   = ws + (size_t)N;          // 8N floats (layer-1 scaled features)
    float* acc1 = ws + (size_t)9 * N;      // 8N floats
    float* g1   = ws + (size_t)N;          // reuse g0 region: 2N floats
    float* acc2 = ws + (size_t)3 * N;      // reuse g0 region: 2N floats

    float* out = (float*)d_out;

    const int gN = (N + TPB - 1) / TPB;
    const int gE = (E + TPB - 1) / TPB;

    k_init_deg<<<gN, TPB, 0, stream>>>(deg, N);
    k_count<<<gE, TPB, 0, stream>>>(col, deg, E);
    k_node1<<<gN, TPB, 0, stream>>>(x, W1, deg, g0, acc1, N);
    k_scatter1<<<gE, TPB, 0, stream>>>(row, col, g0, acc1, E);
    k_node2<<<gN, TPB, 0, stream>>>(deg, acc1, b1, W2, g1, acc2, N);
    k_scatter2<<<gE, TPB, 0, stream>>>(row, col, g1, acc2, E);
    k_final<<<gN, TPB, 0, stream>>>(deg, acc2, b2, out, N);
}

// Round 2
// 754.080 us; speedup vs baseline: 5.9298x; 5.9298x over previous
//
#include <hip/hip_runtime.h>

#define TPB 256
#define NBLK_EDGE 512          // blocks for hist/reorder; chunking must match between them
#define BIN_SHIFT 11
#define BIN_SIZE 2048          // nodes per bin
#define MAXK 256               // max bins (N=500K -> K=245)
#define ROW_BITS 19            // N=500,000 < 2^19
#define ROW_MASK ((1u << ROW_BITS) - 1)

__global__ void k_zero_int(int* __restrict__ p, int n) {
    int i = blockIdx.x * blockDim.x + threadIdx.x;
    if (i < n) p[i] = 0;
}

// Per-block LDS histogram of col>>BIN_SHIFT, merged with K atomics per block.
__global__ void k_hist(const int* __restrict__ col, int E, int chunk, int K,
                       int* __restrict__ ghist) {
    __shared__ int lh[MAXK];
    for (int k = threadIdx.x; k < K; k += blockDim.x) lh[k] = 0;
    __syncthreads();
    int s = blockIdx.x * chunk, e_ = min(s + chunk, E);
    for (int e = s + threadIdx.x; e < e_; e += blockDim.x)
        atomicAdd(&lh[col[e] >> BIN_SHIFT], 1);
    __syncthreads();
    for (int k = threadIdx.x; k < K; k += blockDim.x)
        if (lh[k]) atomicAdd(&ghist[k], lh[k]);
}

// Tiny exclusive scan over K bins (K<=256), writes binBase[0..K] and cursor=binBase.
__global__ void k_scan(const int* __restrict__ ghist, int K,
                       int* __restrict__ binBase, int* __restrict__ cursor) {
    if (blockIdx.x == 0 && threadIdx.x == 0) {
        int run = 0;
        for (int k = 0; k < K; ++k) {
            binBase[k] = run;
            cursor[k] = run;
            run += ghist[k];
        }
        binBase[K] = run;  // == E
    }
}

// Counting-sort reorder: per-block LDS hist -> block-level reservation in global
// cursor -> scatter packed edges (local_col<<19 | row) into bin-contiguous storage.
__global__ void k_reorder(const int* __restrict__ row, const int* __restrict__ col,
                          int E, int chunk, int K,
                          int* __restrict__ cursor, unsigned* __restrict__ packed) {
    __shared__ int lh[MAXK];
    for (int k = threadIdx.x; k < K; k += blockDim.x) lh[k] = 0;
    __syncthreads();
    int s = blockIdx.x * chunk, e_ = min(s + chunk, E);
    for (int e = s + threadIdx.x; e < e_; e += blockDim.x)
        atomicAdd(&lh[col[e] >> BIN_SHIFT], 1);
    __syncthreads();
    for (int k = threadIdx.x; k < K; k += blockDim.x) {
        int c = lh[k];
        lh[k] = c ? atomicAdd(&cursor[k], c) : 0;  // lh becomes running write cursor
    }
    __syncthreads();
    for (int e = s + threadIdx.x; e < e_; e += blockDim.x) {
        int c = col[e];
        int b = c >> BIN_SHIFT;
        unsigned lc = (unsigned)(c & (BIN_SIZE - 1));
        int pos = atomicAdd(&lh[b], 1);            // LDS atomic, returns slot
        packed[pos] = (lc << ROW_BITS) | (unsigned)row[e];
    }
}

// Per-bin degree count via LDS, writes dinv = rsqrt(deg+1).
__global__ void k_bincount(const unsigned* __restrict__ packed, const int* __restrict__ binBase,
                           float* __restrict__ dinv, int N) {
    __shared__ int cnt[BIN_SIZE];
    for (int i = threadIdx.x; i < BIN_SIZE; i += blockDim.x) cnt[i] = 0;
    __syncthreads();
    int bin = blockIdx.x;
    int s = binBase[bin], t = binBase[bin + 1];
    for (int e = s + threadIdx.x; e < t; e += blockDim.x)
        atomicAdd(&cnt[packed[e] >> ROW_BITS], 1);
    __syncthreads();
    int base = bin << BIN_SHIFT;
    int lim = min(BIN_SIZE, N - base);
    for (int n = threadIdx.x; n < lim; n += blockDim.x)
        dinv[base + n] = rsqrtf((float)(cnt[n] + 1));  // +1 self-loop
}

// g0 = dinv * (x @ W1)
__global__ void k_node1(const float* __restrict__ x, const float* __restrict__ W1,
                        const float* __restrict__ dinv_arr, float* __restrict__ g0, int N) {
    int i = blockIdx.x * blockDim.x + threadIdx.x;
    if (i >= N) return;
    float dinv = dinv_arr[i];
    const float4* xv = (const float4*)(x + (size_t)i * 16);
    float4 a0 = xv[0], a1 = xv[1], a2 = xv[2], a3 = xv[3];
    float xl[16] = {a0.x, a0.y, a0.z, a0.w, a1.x, a1.y, a1.z, a1.w,
                    a2.x, a2.y, a2.z, a2.w, a3.x, a3.y, a3.z, a3.w};
    float h[8];
#pragma unroll
    for (int j = 0; j < 8; ++j) h[j] = 0.0f;
#pragma unroll
    for (int k = 0; k < 16; ++k) {
        float xk = xl[k];
#pragma unroll
        for (int j = 0; j < 8; ++j) h[j] += xk * W1[k * 8 + j];
    }
    float4* gv = (float4*)(g0 + (size_t)i * 8);
    gv[0] = make_float4(dinv * h[0], dinv * h[1], dinv * h[2], dinv * h[3]);
    gv[1] = make_float4(dinv * h[4], dinv * h[5], dinv * h[6], dinv * h[7]);
}

// Binned LDS scatter, 8 channels. One workgroup per bin; tile is SoA [ch][2048]
// so bank index = lc&31 (random, no structured conflicts). Writeback folds in
// the self-loop term (acc1 = tile + g0), no global atomics anywhere.
__global__ void __launch_bounds__(1024) k_scatter1(
        const unsigned* __restrict__ packed, const int* __restrict__ binBase,
        const float* __restrict__ g0, float* __restrict__ acc1, int N) {
    __shared__ float tile[8 * BIN_SIZE];  // 64 KB
    for (int i = threadIdx.x; i < 8 * BIN_SIZE; i += blockDim.x) tile[i] = 0.0f;
    __syncthreads();
    int bin = blockIdx.x;
    int s = binBase[bin], t = binBase[bin + 1];
    for (int e = s + (int)threadIdx.x; e < t; e += blockDim.x) {
        unsigned p = packed[e];
        int r = (int)(p & ROW_MASK);
        int lc = (int)(p >> ROW_BITS);
        const float4* gv = (const float4*)(g0 + (size_t)r * 8);
        float4 lo = gv[0], hi = gv[1];
        atomicAdd(&tile[0 * BIN_SIZE + lc], lo.x);
        atomicAdd(&tile[1 * BIN_SIZE + lc], lo.y);
        atomicAdd(&tile[2 * BIN_SIZE + lc], lo.z);
        atomicAdd(&tile[3 * BIN_SIZE + lc], lo.w);
        atomicAdd(&tile[4 * BIN_SIZE + lc], hi.x);
        atomicAdd(&tile[5 * BIN_SIZE + lc], hi.y);
        atomicAdd(&tile[6 * BIN_SIZE + lc], hi.z);
        atomicAdd(&tile[7 * BIN_SIZE + lc], hi.w);
    }
    __syncthreads();
    int base = bin << BIN_SHIFT;
    int lim = min(BIN_SIZE, N - base);
    for (int n = threadIdx.x; n < lim; n += blockDim.x) {
        const float4* sv = (const float4*)(g0 + (size_t)(base + n) * 8);
        float4 slo = sv[0], shi = sv[1];
        float4* av = (float4*)(acc1 + (size_t)(base + n) * 8);
        av[0] = make_float4(tile[0 * BIN_SIZE + n] + slo.x, tile[1 * BIN_SIZE + n] + slo.y,
                            tile[2 * BIN_SIZE + n] + slo.z, tile[3 * BIN_SIZE + n] + slo.w);
        av[1] = make_float4(tile[4 * BIN_SIZE + n] + shi.x, tile[5 * BIN_SIZE + n] + shi.y,
                            tile[6 * BIN_SIZE + n] + shi.z, tile[7 * BIN_SIZE + n] + shi.w);
    }
}

// h = relu(dinv*acc1 + b1); g1 = dinv*(h @ W2)
__global__ void k_node2(const float* __restrict__ dinv_arr, const float* __restrict__ acc1,
                        const float* __restrict__ b1, const float* __restrict__ W2,
                        float* __restrict__ g1, int N) {
    int i = blockIdx.x * blockDim.x + threadIdx.x;
    if (i >= N) return;
    float dinv = dinv_arr[i];
    const float4* av = (const float4*)(acc1 + (size_t)i * 8);
    float4 lo = av[0], hi = av[1];
    float h[8] = {lo.x, lo.y, lo.z, lo.w, hi.x, hi.y, hi.z, hi.w};
    float o0 = 0.0f, o1 = 0.0f;
#pragma unroll
    for (int j = 0; j < 8; ++j) {
        float hj = fmaxf(dinv * h[j] + b1[j], 0.0f);
        o0 += hj * W2[j * 2 + 0];
        o1 += hj * W2[j * 2 + 1];
    }
    ((float2*)g1)[i] = make_float2(dinv * o0, dinv * o1);
}

// Binned LDS scatter, 2 channels. acc2 = tile + g1 (self-loop).
__global__ void __launch_bounds__(1024) k_scatter2(
        const unsigned* __restrict__ packed, const int* __restrict__ binBase,
        const float* __restrict__ g1, float* __restrict__ acc2, int N) {
    __shared__ float tile[2 * BIN_SIZE];  // 16 KB
    for (int i = threadIdx.x; i < 2 * BIN_SIZE; i += blockDim.x) tile[i] = 0.0f;
    __syncthreads();
    int bin = blockIdx.x;
    int s = binBase[bin], t = binBase[bin + 1];
    for (int e = s + (int)threadIdx.x; e < t; e += blockDim.x) {
        unsigned p = packed[e];
        int r = (int)(p & ROW_MASK);
        int lc = (int)(p >> ROW_BITS);
        float2 g = ((const float2*)g1)[r];
        atomicAdd(&tile[0 * BIN_SIZE + lc], g.x);
        atomicAdd(&tile[1 * BIN_SIZE + lc], g.y);
    }
    __syncthreads();
    int base = bin << BIN_SHIFT;
    int lim = min(BIN_SIZE, N - base);
    for (int n = threadIdx.x; n < lim; n += blockDim.x) {
        float2 sg = ((const float2*)g1)[base + n];
        ((float2*)acc2)[base + n] =
            make_float2(tile[0 * BIN_SIZE + n] + sg.x, tile[1 * BIN_SIZE + n] + sg.y);
    }
}

// o = dinv*acc2 + b2; out = log_softmax(o)
__global__ void k_final(const float* __restrict__ dinv_arr, const float* __restrict__ acc2,
                        const float* __restrict__ b2, float* __restrict__ out, int N) {
    int i = blockIdx.x * blockDim.x + threadIdx.x;
    if (i >= N) return;
    float dinv = dinv_arr[i];
    float2 a = ((const float2*)acc2)[i];
    float o0 = dinv * a.x + b2[0];
    float o1 = dinv * a.y + b2[1];
    float m = fmaxf(o0, o1);
    float lse = m + logf(expf(o0 - m) + expf(o1 - m));
    ((float2*)out)[i] = make_float2(o0 - lse, o1 - lse);
}

extern "C" void kernel_launch(void* const* d_in, const int* in_sizes, int n_in,
                              void* d_out, int out_size, void* d_ws, size_t ws_size,
                              hipStream_t stream) {
    const float* x  = (const float*)d_in[0];
    const float* W1 = (const float*)d_in[1];
    const float* b1 = (const float*)d_in[2];
    const float* W2 = (const float*)d_in[3];
    const float* b2 = (const float*)d_in[4];
    const int*   ei = (const int*)d_in[5];

    const int N = in_sizes[0] / 16;
    const int E = in_sizes[5] / 2;
    const int* row = ei;
    const int* col = ei + E;
    const int K = (N + BIN_SIZE - 1) >> BIN_SHIFT;  // 245 for N=500K

    float* ws   = (float*)d_ws;
    float* dinv = ws;                       // N
    float* g0   = ws + (size_t)N;           // 8N
    float* acc1 = ws + (size_t)9 * N;       // 8N
    float* g1   = ws + (size_t)N;           // reuse g0 region (2N) after scatter1
    float* acc2 = ws + (size_t)3 * N;       // reuse g0 region (2N)
    int*   meta = (int*)(ws + (size_t)17 * N);
    int* ghist   = meta;                    // K ints
    int* binBase = meta + MAXK;             // K+1 ints
    int* cursor  = meta + 2 * MAXK + 8;     // K ints
    unsigned* packed = (unsigned*)(meta + 4 * MAXK);  // E uints

    float* out = (float*)d_out;

    const int gN = (N + TPB - 1) / TPB;
    const int chunk = (E + NBLK_EDGE - 1) / NBLK_EDGE;

    k_zero_int<<<1, TPB, 0, stream>>>(ghist, K);
    k_hist   <<<NBLK_EDGE, TPB, 0, stream>>>(col, E, chunk, K, ghist);
    k_scan   <<<1, 64, 0, stream>>>(ghist, K, binBase, cursor);
    k_reorder<<<NBLK_EDGE, TPB, 0, stream>>>(row, col, E, chunk, K, cursor, packed);
    k_bincount<<<K, TPB, 0, stream>>>(packed, binBase, dinv, N);
    k_node1  <<<gN, TPB, 0, stream>>>(x, W1, dinv, g0, N);
    k_scatter1<<<K, 1024, 0, stream>>>(packed, binBase, g0, acc1, N);
    k_node2  <<<gN, TPB, 0, stream>>>(dinv, acc1, b1, W2, g1, N);
    k_scatter2<<<K, 1024, 0, stream>>>(packed, binBase, g1, acc2, N);
    k_final  <<<gN, TPB, 0, stream>>>(dinv, acc2, b2, out, N);
}